// Round 1
// baseline (503.312 us; speedup 1.0000x reference)
//
#include <hip/hip_runtime.h>
#include <cstdint>
#include <cstddef>

#define NTOK 16384
#define HID  4096
#define NEXP 64
#define MT   128   // tokens per GEMM block
#define KT   32    // k-elements per LDS tile
#define TPB_A 128

// ---------------------------------------------------------------------------
// async global->LDS, 16B per lane. LDS dest = wave-uniform base + lane*16.
// ---------------------------------------------------------------------------
__device__ __forceinline__ void gload_lds16(const float* gp, float* lp) {
  __builtin_amdgcn_global_load_lds(
      (const __attribute__((address_space(1))) void*)gp,
      (__attribute__((address_space(3))) void*)lp,
      16, 0, 0);
}

// ---------------------------------------------------------------------------
// Kernel A: K-split GEMM.  part[ks][t][e] = sum over k-range of x[t]·W[e]
// Block: 128 thr (2 waves). tile = 128 tokens x 64 experts, thread = 8x8.
// LDS XOR swizzle: element-slot k4' = k4 ^ (row&7) applied on the GLOBAL
// source address at staging time (global_load_lds writes linearly), and the
// same XOR on the read side -> every ds_read_b128 hits each bank once.
// ---------------------------------------------------------------------------
__global__ __launch_bounds__(TPB_A) void gemm_part_kernel(
    const float* __restrict__ x, const float* __restrict__ W,
    float* __restrict__ part, int KS) {
  const int ntile = NTOK / MT;            // 128
  const int tile  = blockIdx.x % ntile;
  const int ks    = blockIdx.x / ntile;
  const int KRANGE = HID / KS;
  const int NKT    = KRANGE / KT;
  const int k0     = ks * KRANGE;
  const int t0     = tile * MT;

  __shared__ float xs[2][MT * KT];        // 2 x 16 KB
  __shared__ float wsh[2][NEXP * KT];     // 2 x  8 KB

  const int tid  = threadIdx.x;
  const int lane = tid & 63;
  const int wave = tid >> 6;
  const int tg   = tid >> 3;              // 0..15 token group
  const int eg   = tid & 7;               // 0..7  expert group

  float acc[8][8];
#pragma unroll
  for (int i = 0; i < 8; ++i)
#pragma unroll
    for (int j = 0; j < 8; ++j) acc[i][j] = 0.f;

  auto stage = [&](int b, int kt) {
    const int kbase = k0 + kt * KT;
    // x tile: 16 KB = 16 chunks of 1 KB; each wave stages 8 chunks
#pragma unroll
    for (int s = 0; s < 8; ++s) {
      int chunk = s * 2 + wave;
      int Lb  = chunk * 1024 + lane * 16;        // byte offset in xs[b]
      int row = Lb >> 7;                         // token row (128B rows)
      int k4s = (Lb >> 4) & 7;                   // lds slot
      int gk4 = k4s ^ (row & 7);                 // global sub-block (inverse swz)
      const float* gp = x + (size_t)(t0 + row) * HID + kbase + gk4 * 4;
      gload_lds16(gp, &xs[b][chunk * 256]);
    }
    // W tile: 8 KB = 8 chunks; each wave stages 4
#pragma unroll
    for (int s = 0; s < 4; ++s) {
      int chunk = s * 2 + wave;
      int Lb  = chunk * 1024 + lane * 16;
      int e   = Lb >> 7;
      int k4s = (Lb >> 4) & 7;
      int gk4 = k4s ^ ((e >> 3) & 7);
      const float* gp = W + (size_t)e * HID + kbase + gk4 * 4;
      gload_lds16(gp, &wsh[b][chunk * 256]);
    }
  };

  auto compute = [&](int b) {
    for (int k4 = 0; k4 < 8; ++k4) {
      float4 xv[8], wv[8];
#pragma unroll
      for (int i = 0; i < 8; ++i) {
        int t = tg + 16 * i;                      // t&7 == tg&7
        xv[i] = *(const float4*)&xs[b][t * 32 + ((k4 ^ (tg & 7)) << 2)];
      }
#pragma unroll
      for (int j = 0; j < 8; ++j) {
        int e = eg * 8 + j;                       // 8 consecutive experts
        wv[j] = *(const float4*)&wsh[b][e * 32 + ((k4 ^ eg) << 2)];
      }
#pragma unroll
      for (int i = 0; i < 8; ++i)
#pragma unroll
        for (int j = 0; j < 8; ++j) {
          acc[i][j] = fmaf(xv[i].x, wv[j].x, acc[i][j]);
          acc[i][j] = fmaf(xv[i].y, wv[j].y, acc[i][j]);
          acc[i][j] = fmaf(xv[i].z, wv[j].z, acc[i][j]);
          acc[i][j] = fmaf(xv[i].w, wv[j].w, acc[i][j]);
        }
    }
  };

  stage(0, 0);
  __syncthreads();
  for (int kt = 0; kt < NKT; ++kt) {
    if (kt + 1 < NKT) stage((kt + 1) & 1, kt + 1);
    compute(kt & 1);
    __syncthreads();   // drains vmcnt: next tile staged; buffer free for reuse
  }

  float* pb = part + ((size_t)ks * NTOK + t0) * NEXP;
#pragma unroll
  for (int i = 0; i < 8; ++i) {
    int t = tg + 16 * i;
    float4 o0 = make_float4(acc[i][0], acc[i][1], acc[i][2], acc[i][3]);
    float4 o1 = make_float4(acc[i][4], acc[i][5], acc[i][6], acc[i][7]);
    *(float4*)&pb[(size_t)t * NEXP + eg * 8]     = o0;
    *(float4*)&pb[(size_t)t * NEXP + eg * 8 + 4] = o1;
  }
}

// ---------------------------------------------------------------------------
// Kernel B: per-token softmax + top-2 + stats. One wave per token, lane=expert.
// ---------------------------------------------------------------------------
__global__ __launch_bounds__(256) void router_kernel(
    const float* __restrict__ part, float* __restrict__ out,
    float* __restrict__ gstats, int KS) {
  const int lane  = threadIdx.x & 63;
  const int wave  = threadIdx.x >> 6;
  const int tbase = blockIdx.x * 64 + wave * 16;

  float avg_acc = 0.f, ent_acc = 0.f, cnt_acc = 0.f;

  for (int tt = 0; tt < 16; ++tt) {
    const int t = tbase + tt;
    float l = 0.f;
    for (int s = 0; s < KS; ++s)
      l += part[((size_t)s * NTOK + t) * NEXP + lane];

    float m = l;
#pragma unroll
    for (int off = 32; off; off >>= 1) m = fmaxf(m, __shfl_xor(m, off));
    float p = expf(l - m);
    float d = p;
#pragma unroll
    for (int off = 32; off; off >>= 1) d += __shfl_xor(d, off);
    float prob = p / d;

    avg_acc += prob;
    ent_acc += prob * logf(prob + 1e-10f);

    // top-1 (value desc, index asc on ties — matches jax.lax.top_k)
    float v1 = prob; int i1 = lane;
#pragma unroll
    for (int off = 32; off; off >>= 1) {
      float ov = __shfl_xor(v1, off);
      int   oi = __shfl_xor(i1, off);
      if (ov > v1 || (ov == v1 && oi < i1)) { v1 = ov; i1 = oi; }
    }
    // top-2
    float v2 = (lane == i1) ? -1.f : prob; int i2 = lane;
#pragma unroll
    for (int off = 32; off; off >>= 1) {
      float ov = __shfl_xor(v2, off);
      int   oi = __shfl_xor(i2, off);
      if (ov > v2 || (ov == v2 && oi < i2)) { v2 = ov; i2 = oi; }
    }
    cnt_acc += (lane == i1 ? 1.f : 0.f) + (lane == i2 ? 1.f : 0.f);

    if (lane == 0) {
      float wsum = v1 + v2;
      out[2 * t]     = (float)i1;
      out[2 * t + 1] = (float)i2;
      out[2 * NTOK + 2 * t]     = v1 / wsum;
      out[2 * NTOK + 2 * t + 1] = v2 / wsum;
    }
  }

  __shared__ float red[4][NEXP];
  red[wave][lane] = avg_acc;
  __syncthreads();
  if (wave == 0) {
    float s = red[0][lane] + red[1][lane] + red[2][lane] + red[3][lane];
    atomicAdd(&gstats[NEXP + lane], s);
  }
  __syncthreads();
  red[wave][lane] = cnt_acc;
  __syncthreads();
  if (wave == 0) {
    float s = red[0][lane] + red[1][lane] + red[2][lane] + red[3][lane];
    atomicAdd(&gstats[lane], s);
  }
  float e = ent_acc;
#pragma unroll
  for (int off = 32; off; off >>= 1) e += __shfl_xor(e, off);
  __syncthreads();
  if (lane == 0) red[0][wave] = e;
  __syncthreads();
  if (threadIdx.x == 0)
    atomicAdd(&gstats[2 * NEXP], red[0][0] + red[0][1] + red[0][2] + red[0][3]);
}

// ---------------------------------------------------------------------------
// Kernel C: finalize — counts, avg_probs, entropy, gini. 1 block, 64 thr.
// ---------------------------------------------------------------------------
__global__ void finalize_kernel(const float* __restrict__ gstats,
                                float* __restrict__ out) {
  const int e = threadIdx.x;            // 0..63
  const float c   = gstats[e];
  const float avg = gstats[NEXP + e] * (1.0f / NTOK);

  out[2 * NTOK * 2 + e]        = c;     // expert_counts at 65536
  out[2 * NTOK * 2 + NEXP + e] = avg;   // avg_probs at 65600

  __shared__ float cs[NEXP];
  cs[e] = c;
  __syncthreads();

  int rank = 0;
  for (int j = 0; j < NEXP; ++j) {
    float cj = cs[j];
    rank += (cj < c || (cj == c && j < e)) ? 1 : 0;
  }
  float val = (2.0f * (rank + 1) - NEXP - 1) * c;
  float tot = c;
#pragma unroll
  for (int off = 32; off; off >>= 1) {
    val += __shfl_xor(val, off);
    tot += __shfl_xor(tot, off);
  }
  if (e == 0) {
    out[2 * NTOK * 2 + 2 * NEXP]     = -gstats[2 * NEXP] * (1.0f / NTOK); // entropy
    out[2 * NTOK * 2 + 2 * NEXP + 1] = val / (NEXP * tot + 1e-10f);       // gini
  }
}

// ---------------------------------------------------------------------------
extern "C" void kernel_launch(void* const* d_in, const int* in_sizes, int n_in,
                              void* d_out, int out_size, void* d_ws, size_t ws_size,
                              hipStream_t stream) {
  const float* x = (const float*)d_in[0];
  const float* W = (const float*)d_in[1];
  float* out = (float*)d_out;
  float* ws  = (float*)d_ws;

  // choose K-split to fit workspace: KS*NTOK*NEXP*4 bytes of partials + stats
  int KS;
  const size_t slab = (size_t)NTOK * NEXP * 4;
  const size_t stats_bytes = (2 * NEXP + 1) * sizeof(float);
  if      (ws_size >= 8 * slab + stats_bytes) KS = 8;
  else if (ws_size >= 4 * slab + stats_bytes) KS = 4;
  else if (ws_size >= 2 * slab + stats_bytes) KS = 2;
  else                                        KS = 1;

  float* gstats = ws + (size_t)KS * NTOK * NEXP;
  hipMemsetAsync(gstats, 0, stats_bytes, stream);

  gemm_part_kernel<<<dim3((NTOK / MT) * KS), TPB_A, 0, stream>>>(x, W, ws, KS);
  router_kernel<<<dim3(NTOK / 64), 256, 0, stream>>>(ws, out, gstats, KS);
  finalize_kernel<<<dim3(1), 64, 0, stream>>>(gstats, out);
}

// Round 2
// 460.687 us; speedup vs baseline: 1.0925x; 1.0925x over previous
//
#include <hip/hip_runtime.h>
#include <cstdint>
#include <cstddef>

#define NTOK 16384
#define HID  4096
#define NEXP 64
#define LO_SCALE 2048.0f
#define LO_INV   (1.0f/2048.0f)

typedef _Float16 half8  __attribute__((ext_vector_type(8)));
typedef _Float16 half4v __attribute__((ext_vector_type(4)));
typedef float    f32x4  __attribute__((ext_vector_type(4)));

// ---------------------------------------------------------------------------
// Prologue: split W (f32 [64][4096]) into Whi/Wlo f16, lo scaled by 2^11 so
// it stays in f16 normal range (avoids MFMA denormal-flush losing the low bits)
// ---------------------------------------------------------------------------
__global__ __launch_bounds__(256) void wsplit_kernel(
    const float* __restrict__ W, _Float16* __restrict__ whi,
    _Float16* __restrict__ wlo) {
  int i = (blockIdx.x * 256 + threadIdx.x) * 4;
  float4 w = *(const float4*)(W + i);
  float f[4] = {w.x, w.y, w.z, w.w};
  half4v h, l;
#pragma unroll
  for (int j = 0; j < 4; ++j) {
    float hf = __uint_as_float(__float_as_uint(f[j]) & 0xffffe000u);
    h[j] = (_Float16)hf;
    l[j] = (_Float16)((f[j] - hf) * LO_SCALE);
  }
  *(half4v*)(whi + i) = h;
  *(half4v*)(wlo + i) = l;
}

// ---------------------------------------------------------------------------
// Fused: GEMM (fp16-split MFMA) + softmax + top-2 + stats.
// Block = 256 thr = 4 waves. Block owns 32 tokens.
//   wave w: token-half (w&1)*16, K-half (w>>1)*2048.
// Wave computes 16 tokens x 64 experts over its K-half with
// mfma_f32_16x16x32_f16:  A,B frags = 8 consecutive K elems of row (lane&15),
// k-group (lane>>4)*8;  C: col=lane&15 (expert), row=(lane>>4)*4+reg (token).
// ---------------------------------------------------------------------------
__global__ __launch_bounds__(256, 2) void fused_kernel(
    const float* __restrict__ x, const _Float16* __restrict__ whi,
    const _Float16* __restrict__ wlo, float* __restrict__ out,
    float* __restrict__ gstats) {
  __shared__ float red[32][NEXP];   // K-half reduction buffer
  __shared__ float savg[NEXP];
  __shared__ float scnt[NEXP];
  __shared__ float sent;

  const int tid     = threadIdx.x;
  const int lane    = tid & 63;
  const int wv      = tid >> 6;
  const int tokhalf = wv & 1;
  const int khalf   = wv >> 1;
  const int row     = lane & 15;   // token-row / expert-row within 16-tile
  const int g       = lane >> 4;   // k-subgroup 0..3

  if (tid < NEXP) { savg[tid] = 0.f; scnt[tid] = 0.f; }
  if (tid == 0) sent = 0.f;

  const int t0 = blockIdx.x * 32 + tokhalf * 16;
  const float*    xp  = x   + (size_t)(t0 + row) * HID + khalf * 2048 + g * 8;
  const _Float16* whp = whi + (size_t)row * HID        + khalf * 2048 + g * 8;
  const _Float16* wlp = wlo + (size_t)row * HID        + khalf * 2048 + g * 8;
  const size_t estride = (size_t)16 * HID;

  f32x4 acc[4], crs[4];
#pragma unroll
  for (int e = 0; e < 4; ++e) {
    acc[e] = (f32x4){0.f, 0.f, 0.f, 0.f};
    crs[e] = (f32x4){0.f, 0.f, 0.f, 0.f};
  }

#define LDA(KS, P0, P1)                              \
  P0 = *(const float4*)(xp + (KS) * 32);             \
  P1 = *(const float4*)(xp + (KS) * 32 + 4);

#define LDB(KS, BH, BL)                                        \
  _Pragma("unroll")                                            \
  for (int e = 0; e < 4; ++e) {                                \
    BH[e] = *(const half8*)(whp + e * estride + (KS) * 32);    \
    BL[e] = *(const half8*)(wlp + e * estride + (KS) * 32);    \
  }

#define STEP(P0, P1, BH, BL)                                              \
  {                                                                       \
    float ff[8] = {P0.x, P0.y, P0.z, P0.w, P1.x, P1.y, P1.z, P1.w};       \
    half8 ah, al;                                                         \
    _Pragma("unroll")                                                     \
    for (int j = 0; j < 8; ++j) {                                         \
      float hf = __uint_as_float(__float_as_uint(ff[j]) & 0xffffe000u);   \
      ah[j] = (_Float16)hf;                                               \
      al[j] = (_Float16)((ff[j] - hf) * LO_SCALE);                        \
    }                                                                     \
    _Pragma("unroll")                                                     \
    for (int e = 0; e < 4; ++e) {                                         \
      acc[e] = __builtin_amdgcn_mfma_f32_16x16x32_f16(ah, BH[e], acc[e], 0, 0, 0); \
      crs[e] = __builtin_amdgcn_mfma_f32_16x16x32_f16(ah, BL[e], crs[e], 0, 0, 0); \
      crs[e] = __builtin_amdgcn_mfma_f32_16x16x32_f16(al, BH[e], crs[e], 0, 0, 0); \
    }                                                                     \
  }

  float4 xa0, xa1, xb0, xb1;
  half8 bh0[4], bl0[4], bh1[4], bl1[4];

  LDA(0, xa0, xa1)
  LDB(0, bh0, bl0)
  for (int ks = 0; ks < 64; ks += 2) {
    LDA(ks + 1, xb0, xb1)
    LDB(ks + 1, bh1, bl1)
    STEP(xa0, xa1, bh0, bl0)
    if (ks + 2 < 64) {
      LDA(ks + 2, xa0, xa1)
      LDB(ks + 2, bh0, bl0)
    }
    STEP(xb0, xb1, bh1, bl1)
  }

  // merge hi*hi acc with rescaled cross-term acc
  float v[4][4];  // [etile][reg]
#pragma unroll
  for (int e = 0; e < 4; ++e)
#pragma unroll
    for (int r = 0; r < 4; ++r)
      v[e][r] = acc[e][r] + crs[e][r] * LO_INV;

  if (khalf == 1) {
#pragma unroll
    for (int e = 0; e < 4; ++e)
#pragma unroll
      for (int r = 0; r < 4; ++r)
        red[tokhalf * 16 + g * 4 + r][e * 16 + row] = v[e][r];
  }
  __syncthreads();

  if (khalf == 0) {
#pragma unroll
    for (int e = 0; e < 4; ++e)
#pragma unroll
      for (int r = 0; r < 4; ++r)
        v[e][r] += red[tokhalf * 16 + g * 4 + r][e * 16 + row];

    // token t = t0 + g*4 + r lives in the 16 lanes of group g;
    // lane holds experts {e*16+row} for e=0..3.
    float m[4], S[4], PL[4];
#pragma unroll
    for (int r = 0; r < 4; ++r) {
      float mm = fmaxf(fmaxf(v[0][r], v[1][r]), fmaxf(v[2][r], v[3][r]));
#pragma unroll
      for (int off = 1; off < 16; off <<= 1) mm = fmaxf(mm, __shfl_xor(mm, off));
      m[r] = mm;
    }
    float p[4][4];
#pragma unroll
    for (int e = 0; e < 4; ++e)
#pragma unroll
      for (int r = 0; r < 4; ++r)
        p[e][r] = __expf(v[e][r] - m[r]);
#pragma unroll
    for (int r = 0; r < 4; ++r) {
      float s  = p[0][r] + p[1][r] + p[2][r] + p[3][r];
      float pl = p[0][r] * v[0][r] + p[1][r] * v[1][r] +
                 p[2][r] * v[2][r] + p[3][r] * v[3][r];
#pragma unroll
      for (int off = 1; off < 16; off <<= 1) {
        s  += __shfl_xor(s, off);
        pl += __shfl_xor(pl, off);
      }
      S[r] = s; PL[r] = pl;
    }

    // top-2 on logits (order-invariant vs softmax); tiebreak smaller index
    float v1[4], v2[4]; int i1[4], i2[4];
#pragma unroll
    for (int r = 0; r < 4; ++r) {
      float a1 = -3.4e38f, a2 = -3.4e38f; int j1 = 0, j2 = 0;
#pragma unroll
      for (int e = 0; e < 4; ++e) {
        float val = v[e][r]; int idx = e * 16 + row;
        if (val > a1)      { a2 = a1; j2 = j1; a1 = val; j1 = idx; }
        else if (val > a2) { a2 = val; j2 = idx; }
      }
#pragma unroll
      for (int off = 1; off < 16; off <<= 1) {
        float o1 = __shfl_xor(a1, off), o2 = __shfl_xor(a2, off);
        int  oj1 = __shfl_xor(j1, off), oj2 = __shfl_xor(j2, off);
        if (o1 > a1 || (o1 == a1 && oj1 < j1)) {
          if (a1 > o2 || (a1 == o2 && j1 < oj2)) { a2 = a1; j2 = j1; }
          else                                   { a2 = o2; j2 = oj2; }
          a1 = o1; j1 = oj1;
        } else if (o1 > a2 || (o1 == a2 && oj1 < j2)) {
          a2 = o1; j2 = oj1;
        }
      }
      v1[r] = a1; v2[r] = a2; i1[r] = j1; i2[r] = j2;
    }

    float inv[4] = {1.f / S[0], 1.f / S[1], 1.f / S[2], 1.f / S[3]};

    // avg_probs: lane sums its 4 tokens per expert, reduce across groups
#pragma unroll
    for (int e = 0; e < 4; ++e) {
      float s = p[e][0] * inv[0] + p[e][1] * inv[1] +
                p[e][2] * inv[2] + p[e][3] * inv[3];
      s += __shfl_xor(s, 16);
      s += __shfl_xor(s, 32);
      if (lane < 16) atomicAdd(&savg[e * 16 + row], s);
    }

    if (row == 0) {  // one writer lane per token group
      float hsum = 0.f;
#pragma unroll
      for (int r = 0; r < 4; ++r) {
        hsum += m[r] + __logf(S[r]) - PL[r] * inv[r];  // -sum p*log p
        atomicAdd(&scnt[i1[r]], 1.f);
        atomicAdd(&scnt[i2[r]], 1.f);
        int t = t0 + g * 4 + r;
        float e2 = __expf(v2[r] - v1[r]);
        float w1 = 1.f / (1.f + e2);
        out[2 * t]     = (float)i1[r];
        out[2 * t + 1] = (float)i2[r];
        out[2 * NTOK + 2 * t]     = w1;
        out[2 * NTOK + 2 * t + 1] = e2 * w1;
      }
      atomicAdd(&sent, hsum);
    }
  }
  __syncthreads();
  if (tid < NEXP) {
    atomicAdd(&gstats[tid],        scnt[tid]);
    atomicAdd(&gstats[NEXP + tid], savg[tid]);
  }
  if (tid == 0) atomicAdd(&gstats[2 * NEXP], sent);
}

// ---------------------------------------------------------------------------
// Finalize: counts, avg_probs, entropy, gini. 1 block, 64 thr.
// ---------------------------------------------------------------------------
__global__ void finalize_kernel(const float* __restrict__ gstats,
                                float* __restrict__ out) {
  const int e = threadIdx.x;
  const float c   = gstats[e];
  const float avg = gstats[NEXP + e] * (1.0f / NTOK);

  out[4 * NTOK + e]        = c;
  out[4 * NTOK + NEXP + e] = avg;

  __shared__ float cs[NEXP];
  cs[e] = c;
  __syncthreads();

  int rank = 0;
  for (int j = 0; j < NEXP; ++j) {
    float cj = cs[j];
    rank += (cj < c || (cj == c && j < e)) ? 1 : 0;
  }
  float val = (2.0f * (rank + 1) - NEXP - 1) * c;
  float tot = c;
#pragma unroll
  for (int off = 32; off; off >>= 1) {
    val += __shfl_xor(val, off);
    tot += __shfl_xor(tot, off);
  }
  if (e == 0) {
    out[4 * NTOK + 2 * NEXP]     = gstats[2 * NEXP] * (1.0f / NTOK); // entropy
    out[4 * NTOK + 2 * NEXP + 1] = val / (NEXP * tot + 1e-10f);      // gini
  }
}

// ---------------------------------------------------------------------------
extern "C" void kernel_launch(void* const* d_in, const int* in_sizes, int n_in,
                              void* d_out, int out_size, void* d_ws, size_t ws_size,
                              hipStream_t stream) {
  const float* x = (const float*)d_in[0];
  const float* W = (const float*)d_in[1];
  float* out = (float*)d_out;

  _Float16* whi = (_Float16*)d_ws;
  _Float16* wlo = whi + (size_t)NEXP * HID;
  float* gstats = (float*)(wlo + (size_t)NEXP * HID);

  hipMemsetAsync(gstats, 0, (2 * NEXP + 1) * sizeof(float), stream);
  wsplit_kernel<<<dim3((NEXP * HID) / (256 * 4)), 256, 0, stream>>>(W, whi, wlo);
  fused_kernel<<<dim3(NTOK / 32), 256, 0, stream>>>(x, whi, wlo, out, gstats);
  finalize_kernel<<<dim3(1), 64, 0, stream>>>(gstats, out);
}

// Round 4
// 449.207 us; speedup vs baseline: 1.1204x; 1.0256x over previous
//
#include <hip/hip_runtime.h>
#include <cstdint>
#include <cstddef>

#define NTOK 16384
#define HID  4096
#define NEXP 64
#define LO_SCALE 2048.0f
#define LO_INV   (1.0f/2048.0f)

typedef _Float16 half8  __attribute__((ext_vector_type(8)));
typedef _Float16 half4v __attribute__((ext_vector_type(4)));
typedef float    f32x4  __attribute__((ext_vector_type(4)));

// ---------------------------------------------------------------------------
// Prologue: split W (f32 [64][4096]) into Whi/Wlo f16; lo scaled by 2^11 so it
// stays in f16 normal range (avoids MFMA denormal flush losing the low bits).
// ---------------------------------------------------------------------------
__global__ __launch_bounds__(256) void wsplit_kernel(
    const float* __restrict__ W, _Float16* __restrict__ whi,
    _Float16* __restrict__ wlo) {
  int i = (blockIdx.x * 256 + threadIdx.x) * 4;
  float4 w = *(const float4*)(W + i);
  float f[4] = {w.x, w.y, w.z, w.w};
  half4v h, l;
#pragma unroll
  for (int j = 0; j < 4; ++j) {
    float hf = __uint_as_float(__float_as_uint(f[j]) & 0xffffe000u);
    h[j] = (_Float16)hf;
    l[j] = (_Float16)((f[j] - hf) * LO_SCALE);
  }
  *(half4v*)(whi + i) = h;
  *(half4v*)(wlo + i) = l;
}

__device__ __forceinline__ void cvt_split(float4 p0, float4 p1,
                                          half8& ah, half8& al) {
  float ff[8] = {p0.x, p0.y, p0.z, p0.w, p1.x, p1.y, p1.z, p1.w};
#pragma unroll
  for (int j = 0; j < 8; ++j) {
    float hf = __uint_as_float(__float_as_uint(ff[j]) & 0xffffe000u);
    ah[j] = (_Float16)hf;
    al[j] = (_Float16)((ff[j] - hf) * LO_SCALE);
  }
}

// ---------------------------------------------------------------------------
// Fused: GEMM (fp16-split MFMA) + softmax + top-2 + stats.
// Block = 256 thr = 4 waves, all on the SAME 32 tokens; wave wv owns
// K-quarter wv*1024. Wave = two 16-row A-frags (tokens t0..+15, t0+16..+31)
// x 64 experts. Depth-3 x prefetch (4 static buffers), W ping-pong (2 bufs).
// mfma_f32_16x16x32_f16: A/B frag = 8 consecutive K elems of row (lane&15),
// k-group (lane>>4)*8;  C: col=lane&15 (expert), row=(lane>>4)*4+reg (token).
// ---------------------------------------------------------------------------
__global__ __launch_bounds__(256, 2) void fused_kernel(
    const float* __restrict__ x, const _Float16* __restrict__ whi,
    const _Float16* __restrict__ wlo, float* __restrict__ out,
    float* __restrict__ gstats) {
  __shared__ float red[3][32][65];   // K-quarter partials from waves 1..3
  __shared__ float savg[NEXP];
  __shared__ float scnt[NEXP];
  __shared__ float sent;

  const int tid  = threadIdx.x;
  const int lane = tid & 63;
  const int wv   = tid >> 6;        // K-quarter index
  const int row  = lane & 15;
  const int g    = lane >> 4;

  if (tid < NEXP) { savg[tid] = 0.f; scnt[tid] = 0.f; }
  if (tid == 0) sent = 0.f;

  const int t0 = blockIdx.x * 32;
  const float*    xp0 = x   + (size_t)(t0 + row) * HID + wv * 1024 + g * 8;
  const float*    xp1 = xp0 + (size_t)16 * HID;
  const _Float16* whp = whi + (size_t)row * HID + wv * 1024 + g * 8;
  const _Float16* wlp = wlo + (size_t)row * HID + wv * 1024 + g * 8;

  f32x4 acc0[4], crs0[4], acc1[4], crs1[4];
#pragma unroll
  for (int e = 0; e < 4; ++e) {
    acc0[e] = (f32x4){0.f,0.f,0.f,0.f}; crs0[e] = (f32x4){0.f,0.f,0.f,0.f};
    acc1[e] = (f32x4){0.f,0.f,0.f,0.f}; crs1[e] = (f32x4){0.f,0.f,0.f,0.f};
  }

  float4 xb[4][4];      // [buf][a0,a1,b0,b1]
  half8  wh[2][4], wl[2][4];

#define XLD(ks, B) {                                   \
    const int _o = (ks) * 32;                          \
    xb[B][0] = *(const float4*)(xp0 + _o);             \
    xb[B][1] = *(const float4*)(xp0 + _o + 4);         \
    xb[B][2] = *(const float4*)(xp1 + _o);             \
    xb[B][3] = *(const float4*)(xp1 + _o + 4);         \
  }

#define WLD(ks, B) {                                             \
    const int _o = (ks) * 32;                                    \
    _Pragma("unroll")                                            \
    for (int e = 0; e < 4; ++e) {                                \
      wh[B][e] = *(const half8*)(whp + e * 65536 + _o);          \
      wl[B][e] = *(const half8*)(wlp + e * 65536 + _o);          \
    }                                                            \
  }

#define STEP(XB, WB) {                                                        \
    half8 ah0, al0, ah1, al1;                                                 \
    cvt_split(xb[XB][0], xb[XB][1], ah0, al0);                                \
    cvt_split(xb[XB][2], xb[XB][3], ah1, al1);                                \
    _Pragma("unroll")                                                         \
    for (int e = 0; e < 4; ++e) {                                             \
      acc0[e] = __builtin_amdgcn_mfma_f32_16x16x32_f16(ah0, wh[WB][e], acc0[e], 0,0,0); \
      crs0[e] = __builtin_amdgcn_mfma_f32_16x16x32_f16(ah0, wl[WB][e], crs0[e], 0,0,0); \
      crs0[e] = __builtin_amdgcn_mfma_f32_16x16x32_f16(al0, wh[WB][e], crs0[e], 0,0,0); \
      acc1[e] = __builtin_amdgcn_mfma_f32_16x16x32_f16(ah1, wh[WB][e], acc1[e], 0,0,0); \
      crs1[e] = __builtin_amdgcn_mfma_f32_16x16x32_f16(ah1, wl[WB][e], crs1[e], 0,0,0); \
      crs1[e] = __builtin_amdgcn_mfma_f32_16x16x32_f16(al1, wh[WB][e], crs1[e], 0,0,0); \
    }                                                                         \
  }

  XLD(0, 0) XLD(1, 1) XLD(2, 2)
  WLD(0, 0) WLD(1, 1)

  for (int kk = 0; kk < 8; ++kk) {
#pragma unroll
    for (int u = 0; u < 4; ++u) {
      const int K  = kk * 4 + u;
      const int kx = (K + 3 < 32) ? K + 3 : 31;   // clamped dup-loads at tail
      const int kw = (K + 2 < 32) ? K + 2 : 31;
      switch (u) {
        case 0: STEP(0, 0) XLD(kx, 3) WLD(kw, 0) break;
        case 1: STEP(1, 1) XLD(kx, 0) WLD(kw, 1) break;
        case 2: STEP(2, 0) XLD(kx, 1) WLD(kw, 0) break;
        default: STEP(3, 1) XLD(kx, 2) WLD(kw, 1) break;
      }
    }
  }

  // merge hi*hi with rescaled cross-terms
  float v[2][4][4];
#pragma unroll
  for (int e = 0; e < 4; ++e)
#pragma unroll
    for (int r = 0; r < 4; ++r) {
      v[0][e][r] = acc0[e][r] + crs0[e][r] * LO_INV;
      v[1][e][r] = acc1[e][r] + crs1[e][r] * LO_INV;
    }

  if (wv != 0) {
#pragma unroll
    for (int mt = 0; mt < 2; ++mt)
#pragma unroll
      for (int e = 0; e < 4; ++e)
#pragma unroll
        for (int r = 0; r < 4; ++r)
          red[wv - 1][mt * 16 + g * 4 + r][e * 16 + row] = v[mt][e][r];
  }
  __syncthreads();

  if (wv == 0) {
#pragma unroll
    for (int mt = 0; mt < 2; ++mt)
#pragma unroll
      for (int e = 0; e < 4; ++e)
#pragma unroll
        for (int r = 0; r < 4; ++r) {
          const int tr = mt * 16 + g * 4 + r, ec = e * 16 + row;
          v[mt][e][r] += red[0][tr][ec] + red[1][tr][ec] + red[2][tr][ec];
        }

#pragma unroll
    for (int mt = 0; mt < 2; ++mt) {
      float m[4], S[4], PL[4];
#pragma unroll
      for (int r = 0; r < 4; ++r) {
        float mm = fmaxf(fmaxf(v[mt][0][r], v[mt][1][r]),
                         fmaxf(v[mt][2][r], v[mt][3][r]));
#pragma unroll
        for (int off = 1; off < 16; off <<= 1) mm = fmaxf(mm, __shfl_xor(mm, off));
        m[r] = mm;
      }
      float p[4][4];
#pragma unroll
      for (int e = 0; e < 4; ++e)
#pragma unroll
        for (int r = 0; r < 4; ++r)
          p[e][r] = __expf(v[mt][e][r] - m[r]);
#pragma unroll
      for (int r = 0; r < 4; ++r) {
        float s  = p[0][r] + p[1][r] + p[2][r] + p[3][r];
        float pl = p[0][r] * v[mt][0][r] + p[1][r] * v[mt][1][r] +
                   p[2][r] * v[mt][2][r] + p[3][r] * v[mt][3][r];
#pragma unroll
        for (int off = 1; off < 16; off <<= 1) {
          s  += __shfl_xor(s, off);
          pl += __shfl_xor(pl, off);
        }
        S[r] = s; PL[r] = pl;
      }

      // top-2 on logits (order-invariant vs softmax); tiebreak smaller index
      float v1[4], v2[4]; int i1[4], i2[4];
#pragma unroll
      for (int r = 0; r < 4; ++r) {
        float a1 = -3.4e38f, a2 = -3.4e38f; int j1 = 0, j2 = 0;
#pragma unroll
        for (int e = 0; e < 4; ++e) {
          float val = v[mt][e][r]; int idx = e * 16 + row;
          if (val > a1)      { a2 = a1; j2 = j1; a1 = val; j1 = idx; }
          else if (val > a2) { a2 = val; j2 = idx; }
        }
#pragma unroll
        for (int off = 1; off < 16; off <<= 1) {
          float o1 = __shfl_xor(a1, off), o2 = __shfl_xor(a2, off);
          int  oj1 = __shfl_xor(j1, off), oj2 = __shfl_xor(j2, off);
          if (o1 > a1 || (o1 == a1 && oj1 < j1)) {
            if (a1 > o2 || (a1 == o2 && j1 < oj2)) { a2 = a1; j2 = j1; }
            else                                   { a2 = o2; j2 = oj2; }
            a1 = o1; j1 = oj1;
          } else if (o1 > a2 || (o1 == a2 && oj1 < j2)) {
            a2 = o1; j2 = oj1;
          }
        }
        v1[r] = a1; v2[r] = a2; i1[r] = j1; i2[r] = j2;
      }

      float inv[4] = {1.f / S[0], 1.f / S[1], 1.f / S[2], 1.f / S[3]};

#pragma unroll
      for (int e = 0; e < 4; ++e) {
        float s = p[e][0] * inv[0] + p[e][1] * inv[1] +
                  p[e][2] * inv[2] + p[e][3] * inv[3];
        s += __shfl_xor(s, 16);
        s += __shfl_xor(s, 32);
        if (lane < 16) atomicAdd(&savg[e * 16 + row], s);
      }

      if (row == 0) {   // one writer lane per token group
        float hsum = 0.f;
#pragma unroll
        for (int r = 0; r < 4; ++r) {
          hsum += m[r] + __logf(S[r]) - PL[r] * inv[r];
          atomicAdd(&scnt[i1[r]], 1.f);
          atomicAdd(&scnt[i2[r]], 1.f);
          int t = t0 + mt * 16 + g * 4 + r;
          float e2 = __expf(v2[r] - v1[r]);
          float w1 = 1.f / (1.f + e2);
          out[2 * t]     = (float)i1[r];
          out[2 * t + 1] = (float)i2[r];
          out[2 * NTOK + 2 * t]     = w1;
          out[2 * NTOK + 2 * t + 1] = e2 * w1;
        }
        atomicAdd(&sent, hsum);
      }
    }
  }
  __syncthreads();
  if (tid < NEXP) {
    atomicAdd(&gstats[tid],        scnt[tid]);
    atomicAdd(&gstats[NEXP + tid], savg[tid]);
  }
  if (tid == 0) atomicAdd(&gstats[2 * NEXP], sent);
}

// ---------------------------------------------------------------------------
// Finalize: counts, avg_probs, entropy, gini. 1 block, 64 thr.
// ---------------------------------------------------------------------------
__global__ void finalize_kernel(const float* __restrict__ gstats,
                                float* __restrict__ out) {
  const int e = threadIdx.x;
  const float c   = gstats[e];
  const float avg = gstats[NEXP + e] * (1.0f / NTOK);

  out[4 * NTOK + e]        = c;
  out[4 * NTOK + NEXP + e] = avg;

  __shared__ float cs[NEXP];
  cs[e] = c;
  __syncthreads();

  int rank = 0;
  for (int j = 0; j < NEXP; ++j) {
    float cj = cs[j];
    rank += (cj < c || (cj == c && j < e)) ? 1 : 0;
  }
  float val = (2.0f * (rank + 1) - NEXP - 1) * c;
  float tot = c;
#pragma unroll
  for (int off = 32; off; off >>= 1) {
    val += __shfl_xor(val, off);
    tot += __shfl_xor(tot, off);
  }
  if (e == 0) {
    out[4 * NTOK + 2 * NEXP]     = gstats[2 * NEXP] * (1.0f / NTOK); // entropy
    out[4 * NTOK + 2 * NEXP + 1] = val / (NEXP * tot + 1e-10f);      // gini
  }
}

// ---------------------------------------------------------------------------
extern "C" void kernel_launch(void* const* d_in, const int* in_sizes, int n_in,
                              void* d_out, int out_size, void* d_ws, size_t ws_size,
                              hipStream_t stream) {
  const float* x = (const float*)d_in[0];
  const float* W = (const float*)d_in[1];
  float* out = (float*)d_out;

  _Float16* whi = (_Float16*)d_ws;
  _Float16* wlo = whi + (size_t)NEXP * HID;
  float* gstats = (float*)(wlo + (size_t)NEXP * HID);

  hipMemsetAsync(gstats, 0, (2 * NEXP + 1) * sizeof(float), stream);
  wsplit_kernel<<<dim3((NEXP * HID) / (256 * 4)), 256, 0, stream>>>(W, whi, wlo);
  fused_kernel<<<dim3(NTOK / 32), 256, 0, stream>>>(x, whi, wlo, out, gstats);
  finalize_kernel<<<dim3(1), 64, 0, stream>>>(gstats, out);
}